// Round 14
// baseline (1217.426 us; speedup 1.0000x reference)
//
#include <hip/hip_runtime.h>
#include <hip/hip_fp16.h>

// Problem constants (fixed by the reference file)
#define NN 50000     // nodes
#define NE 800000    // edges
#define HD 64        // feature dim (in and hidden)
#define NG 512       // graphs
#define NBK 196      // buckets: col >> 8, max 49999>>8 = 195
#define NBL 196      // edge blocks of 4096: ceil(NE/4096)
#define M_CNT (NBK * NBL)       // 38416 counts
#define NBS 151                 // scan blocks: ceil(M_CNT/256)
#define GEMM_BLOCKS 3125        // NN/16
#define NGB 782                 // gather blocks: ceil(NN/64) col-tiles

// Math: with h' = dinv*h (stored fp16, SINGLE rounding from fp32):
//   out[c] = dinv[c] * (sum_src h'[src] + h'[c]) + b.
// Gather is EDGE-PARALLEL: a block owns 64 consecutive cols (their edges are
// contiguous in the bucket-sorted esrc stream) and accumulates gathered rows
// into a 16 KB LDS fp32 tile via ds_add_f32 — no per-node wave chains, 4+
// independent row gathers in flight per wave at 8 blocks/CU occupancy.
// esrc packs src (low 16b) | col&63 (bits 16..21).

// ---------------------------------------------------------------------------
// Pass A: per-(block,bucket) edge counts via LDS histogram (no global atomics)
// + graph node counts via sorted-batch boundary detection + zero pooled[].
__global__ __launch_bounds__(256) void bucket_count(const int* __restrict__ col,
                                                    const int* __restrict__ batch,
                                                    int* __restrict__ counts,
                                                    int* __restrict__ beg,
                                                    int* __restrict__ endx,
                                                    float* __restrict__ pooled) {
    __shared__ int hist[256];
    int tid = threadIdx.x, blk = blockIdx.x;
    hist[tid] = 0;
    __syncthreads();
    int base = blk * 4096;
#pragma unroll
    for (int k = 0; k < 16; ++k) {
        int e = base + k * 256 + tid;
        if (e < NE) atomicAdd(&hist[col[e] >> 8], 1);
    }
    int t = blk * 256 + tid;
    if (t < NG * HD) pooled[t] = 0.f;          // 50176 threads >= 32768
    if (t < NN) {
        int g = batch[t];
        if (t == 0 || batch[t - 1] != g) beg[g] = t;
        if (t == NN - 1 || batch[t + 1] != g) endx[g] = t + 1;
    }
    __syncthreads();
    if (tid < NBK) counts[tid * NBL + blk] = hist[tid];  // bucket-major
}

// ---- 3-stage exclusive scan over counts[M_CNT] ----------------------------
__global__ __launch_bounds__(256) void block_reduce(const int* __restrict__ src,
                                                    int* __restrict__ bsum) {
    __shared__ int ws[4];
    int tid = threadIdx.x, lane = tid & 63, wid = tid >> 6;
    int i = blockIdx.x * 256 + tid;
    int v = (i < M_CNT) ? src[i] : 0;
#pragma unroll
    for (int off = 32; off > 0; off >>= 1) v += __shfl_down(v, off, 64);
    if (lane == 0) ws[wid] = v;
    __syncthreads();
    if (tid == 0) bsum[blockIdx.x] = ws[0] + ws[1] + ws[2] + ws[3];
}

__global__ __launch_bounds__(64) void scan_bsum(int* __restrict__ bsum) {
    int lane = threadIdx.x;
    int carry = 0;
    for (int base = 0; base < NBS; base += 64) {
        int i = base + lane;
        int v = (i < NBS) ? bsum[i] : 0;
        int inc = v;
#pragma unroll
        for (int off = 1; off < 64; off <<= 1) {
            int t = __shfl_up(inc, off, 64);
            if (lane >= off) inc += t;
        }
        if (i < NBS) bsum[i] = carry + inc - v;  // exclusive
        carry += __shfl(inc, 63, 64);
    }
}

__global__ __launch_bounds__(256) void block_scan(const int* __restrict__ src,
                                                  const int* __restrict__ bsum,
                                                  int* __restrict__ dst) {
    __shared__ int ws[4];
    int tid = threadIdx.x, lane = tid & 63, wid = tid >> 6;
    int i = blockIdx.x * 256 + tid;
    int v = (i < M_CNT) ? src[i] : 0;
    int inc = v;
#pragma unroll
    for (int off = 1; off < 64; off <<= 1) {
        int t = __shfl_up(inc, off, 64);
        if (lane >= off) inc += t;
    }
    if (lane == 63) ws[wid] = inc;
    __syncthreads();
    int woff = 0;
    for (int k = 0; k < wid; ++k) woff += ws[k];
    if (i < M_CNT) dst[i] = bsum[blockIdx.x] + woff + inc - v;
}

// ---------------------------------------------------------------------------
// Fused: blocks [0,GEMM_BLOCKS) do h32 = x @ W1 (fp32 out, scaled to fp16 by
// csr_build); blocks [GEMM_BLOCKS, +NBL) scatter edges into packed[].
__global__ __launch_bounds__(256) void gemm1_scatter(const float* __restrict__ x,
                                                     const float* __restrict__ W1,
                                                     float* __restrict__ h32,
                                                     const int* __restrict__ row,
                                                     const int* __restrict__ col,
                                                     const int* __restrict__ counts_ex,
                                                     unsigned* __restrict__ packed) {
    if (blockIdx.x < GEMM_BLOCKS) {
        __shared__ float Ws[64][64];   // 16 KB
        __shared__ float Is[16][64];   // 4 KB
        int t = threadIdx.x;
        for (int i = t; i < 64 * 64; i += 256) Ws[i >> 6][i & 63] = W1[i];
        int row0 = blockIdx.x * 16;
        for (int i = t; i < 16 * 64; i += 256)
            Is[i >> 6][i & 63] = x[(row0 + (i >> 6)) * HD + (i & 63)];
        __syncthreads();
        int c = t & 63, r4 = t >> 6;
        float a0 = 0.f, a1 = 0.f, a2 = 0.f, a3 = 0.f;
#pragma unroll
        for (int k = 0; k < 64; ++k) {
            float w = Ws[k][c];
            a0 += Is[r4 + 0][k] * w;
            a1 += Is[r4 + 4][k] * w;
            a2 += Is[r4 + 8][k] * w;
            a3 += Is[r4 + 12][k] * w;
        }
        h32[(row0 + r4 + 0) * HD + c] = a0;
        h32[(row0 + r4 + 4) * HD + c] = a1;
        h32[(row0 + r4 + 8) * HD + c] = a2;
        h32[(row0 + r4 + 12) * HD + c] = a3;
    } else {
        __shared__ int cur[256];
        int tid = threadIdx.x, blk = blockIdx.x - GEMM_BLOCKS;
        cur[tid] = 0;
        __syncthreads();
        int base = blk * 4096;
#pragma unroll
        for (int k = 0; k < 16; ++k) {
            int e = base + k * 256 + tid;
            if (e < NE) {
                int c = col[e], r = row[e];
                int b = c >> 8;
                int lpos = atomicAdd(&cur[b], 1);
                int pos = counts_ex[b * NBL + blk] + lpos;
                packed[pos] = (unsigned)r | ((unsigned)(c & 255) << 16);
            }
        }
    }
}

// ---------------------------------------------------------------------------
// Fused CSR build: per 256-col bucket — (1) histogram+scan -> rowptr/dinv,
// (1.5) h16 = fp16(dinv * h32) for this bucket's rows [single rounding],
// (2) fill esrc = src | ((col&63)<<16) via LDS cursors.
__global__ __launch_bounds__(256) void csr_build(const unsigned* __restrict__ packed,
                                                 const int* __restrict__ counts_ex,
                                                 int* __restrict__ rowptr,
                                                 float* __restrict__ dinv,
                                                 const float* __restrict__ h32,
                                                 __half* __restrict__ h16,
                                                 unsigned* __restrict__ esrc) {
    __shared__ int hist[256];
    __shared__ int ws[4];
    __shared__ int lrp[256];
    __shared__ float sdinv[256];
    int bkt = blockIdx.x, tid = threadIdx.x;
    int s = counts_ex[bkt * NBL];
    int e = (bkt == NBK - 1) ? NE : counts_ex[(bkt + 1) * NBL];
    hist[tid] = 0;
    __syncthreads();
    for (int j = s + tid; j < e; j += 256)
        atomicAdd(&hist[(packed[j] >> 16) & 255], 1);
    __syncthreads();
    int lane = tid & 63, wid = tid >> 6;
    int v = hist[tid], inc = v;
#pragma unroll
    for (int off = 1; off < 64; off <<= 1) {
        int t = __shfl_up(inc, off, 64);
        if (lane >= off) inc += t;
    }
    if (lane == 63) ws[wid] = inc;
    __syncthreads();
    int woff = 0;
    for (int k = 0; k < wid; ++k) woff += ws[k];
    int excl = s + woff + inc - v;               // exclusive scan
    int node = bkt * 256 + tid;
    float dv = rsqrtf((float)(v + 1));           // +1 self-loop
    if (node < NN) {
        rowptr[node] = excl;
        dinv[node] = dv;
    }
    if (bkt == 0 && tid == 0) rowptr[NN] = NE;
    lrp[tid] = excl;
    sdinv[tid] = dv;
    hist[tid] = 0;                               // reuse as fill cursor
    __syncthreads();
    // (1.5) scale rows of this bucket: h16 = fp16(dinv * h32)
    {
        int nrows = (bkt == NBK - 1) ? (NN - 195 * 256) : 256;
        const float2* hb32 = (const float2*)(h32 + (size_t)bkt * 256 * HD);
        __half2* hb16 = (__half2*)(h16 + (size_t)bkt * 256 * HD);
        for (int i = tid; i < nrows * 32; i += 256) {
            float d = sdinv[i >> 5];
            float2 f = hb32[i];
            hb16[i] = __floats2half2_rn(d * f.x, d * f.y);
        }
    }
    // (2) fill: src | (col&63)<<16
    for (int j = s + tid; j < e; j += 256) {
        unsigned p = packed[j];
        int lc = (p >> 16) & 255;
        int slot = lrp[lc] + atomicAdd(&hist[lc], 1);
        esrc[slot] = (p & 0xFFFFu) | ((unsigned)(lc & 63) << 16);
    }
}

// ---------------------------------------------------------------------------
// h16 = dinv * (relu(in16) @ W)   (layers 2,3) — dinv in fp32 epilogue
__global__ __launch_bounds__(256) void gemm64_f16(const __half* __restrict__ in,
                                                  const float* __restrict__ W,
                                                  const float* __restrict__ dinv,
                                                  __half* __restrict__ out) {
    __shared__ float Ws[64][64];
    __shared__ float Is[16][64];
    __shared__ float sdinv[16];
    int t = threadIdx.x;
    for (int i = t; i < 64 * 64; i += 256) Ws[i >> 6][i & 63] = W[i];
    int row0 = blockIdx.x * 16;
    if (t < 16) sdinv[t] = dinv[row0 + t];
    const __half2* in2 = (const __half2*)(in + (size_t)row0 * HD);
    for (int i = t; i < 16 * 32; i += 256) {
        float2 v = __half22float2(in2[i]);
        int r = i >> 5, c2 = (i & 31) * 2;
        Is[r][c2]     = fmaxf(v.x, 0.f);
        Is[r][c2 + 1] = fmaxf(v.y, 0.f);
    }
    __syncthreads();
    int c = t & 63, r4 = t >> 6;
    float a0 = 0.f, a1 = 0.f, a2 = 0.f, a3 = 0.f;
#pragma unroll
    for (int k = 0; k < 64; ++k) {
        float w = Ws[k][c];
        a0 += Is[r4 + 0][k] * w;
        a1 += Is[r4 + 4][k] * w;
        a2 += Is[r4 + 8][k] * w;
        a3 += Is[r4 + 12][k] * w;
    }
    out[(row0 + r4 + 0) * HD + c] = __float2half(a0 * sdinv[r4 + 0]);
    out[(row0 + r4 + 4) * HD + c] = __float2half(a1 * sdinv[r4 + 4]);
    out[(row0 + r4 + 8) * HD + c] = __float2half(a2 * sdinv[r4 + 8]);
    out[(row0 + r4 + 12) * HD + c] = __float2half(a3 * sdinv[r4 + 12]);
}

// ---------------------------------------------------------------------------
// Edge-parallel gather: block owns cols [64*blk, 64*blk+64); their edges are
// contiguous [rowptr[cmin], rowptr[cend]). 8 half-waves stream edges stride-8
// (lane = 32*p + c: 2 edges per VMEM, 32 half2 channels each), accumulate
// into a 16 KB LDS fp32 tile via ds_add_f32. Epilogue: + self + bias, scale.
template <bool POOL>
__global__ __launch_bounds__(256) void gather_ep(const __half* __restrict__ hp,
                                                 const int* __restrict__ rowptr,
                                                 const unsigned* __restrict__ esrc,
                                                 const float* __restrict__ dinv,
                                                 const float* __restrict__ b,
                                                 __half* __restrict__ out16,
                                                 const int* __restrict__ batch,
                                                 float* __restrict__ pooled) {
    __shared__ float acc[64 * HD];               // 16 KB
    int tid = threadIdx.x, lane = tid & 63, wid = tid >> 6;
    int p = lane >> 5, c = lane & 31;            // edge-of-pair, half2 channel
    int cmin = blockIdx.x * 64;
    for (int i = tid; i < 64 * HD; i += 256) acc[i] = 0.f;
    __syncthreads();
    int cend = cmin + 64; if (cend > NN) cend = NN;
    int s = rowptr[cmin], e = rowptr[cend];
    const __half2* hv = (const __half2*)hp;
    int j = s + 2 * wid + p;                     // this lane's edge slot
    for (; j + 24 < e; j += 32) {                // 4 edges in flight / wave
        unsigned u0 = esrc[j], u1 = esrc[j + 8], u2 = esrc[j + 16], u3 = esrc[j + 24];
        float2 f0 = __half22float2(hv[(u0 & 0xFFFFu) * 32 + c]);
        float2 f1 = __half22float2(hv[(u1 & 0xFFFFu) * 32 + c]);
        float2 f2 = __half22float2(hv[(u2 & 0xFFFFu) * 32 + c]);
        float2 f3 = __half22float2(hv[(u3 & 0xFFFFu) * 32 + c]);
        int l0 = u0 >> 16, l1 = u1 >> 16, l2 = u2 >> 16, l3 = u3 >> 16;
        atomicAdd(&acc[l0 * HD + 2 * c], f0.x);
        atomicAdd(&acc[l0 * HD + 2 * c + 1], f0.y);
        atomicAdd(&acc[l1 * HD + 2 * c], f1.x);
        atomicAdd(&acc[l1 * HD + 2 * c + 1], f1.y);
        atomicAdd(&acc[l2 * HD + 2 * c], f2.x);
        atomicAdd(&acc[l2 * HD + 2 * c + 1], f2.y);
        atomicAdd(&acc[l3 * HD + 2 * c], f3.x);
        atomicAdd(&acc[l3 * HD + 2 * c + 1], f3.y);
    }
    for (; j < e; j += 8) {
        unsigned u = esrc[j];
        float2 f = __half22float2(hv[(u & 0xFFFFu) * 32 + c]);
        int l = u >> 16;
        atomicAdd(&acc[l * HD + 2 * c], f.x);
        atomicAdd(&acc[l * HD + 2 * c + 1], f.y);
    }
    __syncthreads();
    // epilogue: 64 rows x 32 half2-chunks, 8 per thread
    for (int i = tid; i < 64 * 32; i += 256) {
        int r = i >> 5, cc = i & 31;
        int node = cmin + r;
        if (node >= NN) continue;
        float di = dinv[node];
        float2 self = __half22float2(hv[node * 32 + cc]);   // h' pre-scaled
        float ax = acc[r * HD + 2 * cc], ay = acc[r * HD + 2 * cc + 1];
        float2 bb = ((const float2*)b)[cc];
        float vx = di * (ax + self.x) + bb.x;
        float vy = di * (ay + self.y) + bb.y;
        if (POOL) {
            int g = batch[node];
            atomicAdd(&pooled[g * HD + 2 * cc], vx);
            atomicAdd(&pooled[g * HD + 2 * cc + 1], vy);
        } else {
            ((__half2*)out16)[node * 32 + cc] = __floats2half2_rn(vx, vy);
        }
    }
}

// out[g] = (pooled[g,:]/max(cnt,1)) . lin_W + lin_b   — one wave per graph
__global__ __launch_bounds__(64) void final_kernel(const float* __restrict__ pooled,
                                                   const int* __restrict__ beg,
                                                   const int* __restrict__ endx,
                                                   const float* __restrict__ lin_W,
                                                   const float* __restrict__ lin_b,
                                                   float* __restrict__ out) {
    int g = blockIdx.x, d = threadIdx.x;
    float cnt = (float)(endx[g] - beg[g]);
    float v = pooled[g * HD + d] / fmaxf(cnt, 1.f) * lin_W[d];
#pragma unroll
    for (int off = 32; off > 0; off >>= 1) v += __shfl_down(v, off, 64);
    if (d == 0) out[g] = v + lin_b[0];
}

// ---------------------------------------------------------------------------
extern "C" void kernel_launch(void* const* d_in, const int* in_sizes, int n_in,
                              void* d_out, int out_size, void* d_ws, size_t ws_size,
                              hipStream_t stream) {
    const float* x     = (const float*)d_in[0];
    const float* W1    = (const float*)d_in[1];
    const float* b1    = (const float*)d_in[2];
    const float* W2    = (const float*)d_in[3];
    const float* b2    = (const float*)d_in[4];
    const float* W3    = (const float*)d_in[5];
    const float* b3    = (const float*)d_in[6];
    const float* lin_W = (const float*)d_in[7];
    const float* lin_b = (const float*)d_in[8];
    const int* edge_index = (const int*)d_in[9];   // [2, NE]: row then col
    const int* batch      = (const int*)d_in[10];
    const int* row = edge_index;
    const int* col = edge_index + NE;
    float* out = (float*)d_out;

    // workspace layout (4B units):
    // [h32 NN*HD float][h16 NN*HD half][A16 NN*HD half][esrc NE][packed NE]
    // [counts M][counts_ex M][rowptr NN+2][dinv NN][bsum 256]
    // [pooled NG*HD][beg NG][endx NG]        total ~33 MB
    float*    h32       = (float*)d_ws;
    __half*   h16       = (__half*)(h32 + (size_t)NN * HD);
    __half*   A16       = h16 + (size_t)NN * HD;
    unsigned* esrc      = (unsigned*)(A16 + (size_t)NN * HD);
    unsigned* packed    = esrc + NE;
    int*      counts    = (int*)(packed + NE);
    int*      counts_ex = counts + M_CNT;
    int*      rowptr    = counts_ex + M_CNT;
    float*    dinv      = (float*)(rowptr + NN + 2);
    int*      bsum      = (int*)(dinv + NN);
    float*    pooled    = (float*)(bsum + 256);
    int*      beg       = (int*)(pooled + NG * HD);
    int*      endx      = beg + NG;

    // CSR build: count(+zero pooled) -> scan -> (scatter fused w/ gemm1)
    //            -> fused rowptr+scale+fill
    bucket_count<<<NBL, 256, 0, stream>>>(col, batch, counts, beg, endx, pooled);
    block_reduce<<<NBS, 256, 0, stream>>>(counts, bsum);
    scan_bsum<<<1, 64, 0, stream>>>(bsum);
    block_scan<<<NBS, 256, 0, stream>>>(counts, bsum, counts_ex);
    gemm1_scatter<<<GEMM_BLOCKS + NBL, 256, 0, stream>>>(x, W1, h32, row, col,
                                                         counts_ex, packed);
    csr_build<<<NBK, 256, 0, stream>>>(packed, counts_ex, rowptr, dinv,
                                       h32, h16, esrc);

    // Layer 1 aggregate: h16(=h1') -> A16
    gather_ep<false><<<NGB, 256, 0, stream>>>(h16, rowptr, esrc, dinv, b1, A16,
                                              batch, pooled);
    // Layer 2: relu(A16) -> h16(=h2') -> A16
    gemm64_f16<<<GEMM_BLOCKS, 256, 0, stream>>>(A16, W2, dinv, h16);
    gather_ep<false><<<NGB, 256, 0, stream>>>(h16, rowptr, esrc, dinv, b2, A16,
                                              batch, pooled);
    // Layer 3: relu(A16) -> h16(=h3') -> pooled (fused)
    gemm64_f16<<<GEMM_BLOCKS, 256, 0, stream>>>(A16, W3, dinv, h16);
    gather_ep<true><<<NGB, 256, 0, stream>>>(h16, rowptr, esrc, dinv, b3, nullptr,
                                             batch, pooled);

    final_kernel<<<NG, 64, 0, stream>>>(pooled, beg, endx, lin_W, lin_b, out);
}

// Round 15
// 261.730 us; speedup vs baseline: 4.6514x; 4.6514x over previous
//
#include <hip/hip_runtime.h>
#include <hip/hip_fp16.h>

// Problem constants (fixed by the reference file)
#define NN 50000     // nodes
#define NE 800000    // edges
#define HD 64        // feature dim (in and hidden)
#define NG 512       // graphs
#define NBK 196      // buckets: col >> 8, max 49999>>8 = 195
#define NBL 196      // edge blocks of 4096: ceil(NE/4096)
#define M_CNT (NBK * NBL)       // 38416 counts
#define NBS 151                 // scan blocks: ceil(M_CNT/256)
#define GEMM_BLOCKS 3125        // NN/16

// Math: with h' = dinv*h (stored fp16, SINGLE rounding from fp32):
//   out[c] = dinv[c] * (sum_src h'[src] + h'[c]) + b.
// Gather: node-per-wave, weight-free, scalar esrc stream. Main loop does
// unmasked 8-edge batches (4 row-gathers in flight); the remainder is ONE
// masked 8-edge batch — invalid slots clamp to the batch's first src (L1-hot)
// and are zero-multiplied. No serial 2-edge tail (R13's regression), no
// shuffles inside loops (R8/R10 bug class), no LDS atomics (R14 disaster).

// ---------------------------------------------------------------------------
// Pass A: per-(block,bucket) edge counts via LDS histogram (no global atomics)
// + graph node counts via sorted-batch boundary detection + zero pooled[].
__global__ __launch_bounds__(256) void bucket_count(const int* __restrict__ col,
                                                    const int* __restrict__ batch,
                                                    int* __restrict__ counts,
                                                    int* __restrict__ beg,
                                                    int* __restrict__ endx,
                                                    float* __restrict__ pooled) {
    __shared__ int hist[256];
    int tid = threadIdx.x, blk = blockIdx.x;
    hist[tid] = 0;
    __syncthreads();
    int base = blk * 4096;
#pragma unroll
    for (int k = 0; k < 16; ++k) {
        int e = base + k * 256 + tid;
        if (e < NE) atomicAdd(&hist[col[e] >> 8], 1);
    }
    int t = blk * 256 + tid;
    if (t < NG * HD) pooled[t] = 0.f;          // 50176 threads >= 32768
    if (t < NN) {
        int g = batch[t];
        if (t == 0 || batch[t - 1] != g) beg[g] = t;
        if (t == NN - 1 || batch[t + 1] != g) endx[g] = t + 1;
    }
    __syncthreads();
    if (tid < NBK) counts[tid * NBL + blk] = hist[tid];  // bucket-major
}

// ---- 3-stage exclusive scan over counts[M_CNT] ----------------------------
__global__ __launch_bounds__(256) void block_reduce(const int* __restrict__ src,
                                                    int* __restrict__ bsum) {
    __shared__ int ws[4];
    int tid = threadIdx.x, lane = tid & 63, wid = tid >> 6;
    int i = blockIdx.x * 256 + tid;
    int v = (i < M_CNT) ? src[i] : 0;
#pragma unroll
    for (int off = 32; off > 0; off >>= 1) v += __shfl_down(v, off, 64);
    if (lane == 0) ws[wid] = v;
    __syncthreads();
    if (tid == 0) bsum[blockIdx.x] = ws[0] + ws[1] + ws[2] + ws[3];
}

__global__ __launch_bounds__(64) void scan_bsum(int* __restrict__ bsum) {
    int lane = threadIdx.x;
    int carry = 0;
    for (int base = 0; base < NBS; base += 64) {
        int i = base + lane;
        int v = (i < NBS) ? bsum[i] : 0;
        int inc = v;
#pragma unroll
        for (int off = 1; off < 64; off <<= 1) {
            int t = __shfl_up(inc, off, 64);
            if (lane >= off) inc += t;
        }
        if (i < NBS) bsum[i] = carry + inc - v;  // exclusive
        carry += __shfl(inc, 63, 64);
    }
}

__global__ __launch_bounds__(256) void block_scan(const int* __restrict__ src,
                                                  const int* __restrict__ bsum,
                                                  int* __restrict__ dst) {
    __shared__ int ws[4];
    int tid = threadIdx.x, lane = tid & 63, wid = tid >> 6;
    int i = blockIdx.x * 256 + tid;
    int v = (i < M_CNT) ? src[i] : 0;
    int inc = v;
#pragma unroll
    for (int off = 1; off < 64; off <<= 1) {
        int t = __shfl_up(inc, off, 64);
        if (lane >= off) inc += t;
    }
    if (lane == 63) ws[wid] = inc;
    __syncthreads();
    int woff = 0;
    for (int k = 0; k < wid; ++k) woff += ws[k];
    if (i < M_CNT) dst[i] = bsum[blockIdx.x] + woff + inc - v;
}

// ---------------------------------------------------------------------------
// Fused: blocks [0,GEMM_BLOCKS) do h32 = x @ W1 (fp32 out, scaled to fp16 by
// csr_build); blocks [GEMM_BLOCKS, +NBL) scatter edges into packed[].
__global__ __launch_bounds__(256) void gemm1_scatter(const float* __restrict__ x,
                                                     const float* __restrict__ W1,
                                                     float* __restrict__ h32,
                                                     const int* __restrict__ row,
                                                     const int* __restrict__ col,
                                                     const int* __restrict__ counts_ex,
                                                     unsigned* __restrict__ packed) {
    if (blockIdx.x < GEMM_BLOCKS) {
        __shared__ float Ws[64][64];   // 16 KB
        __shared__ float Is[16][64];   // 4 KB
        int t = threadIdx.x;
        for (int i = t; i < 64 * 64; i += 256) Ws[i >> 6][i & 63] = W1[i];
        int row0 = blockIdx.x * 16;
        for (int i = t; i < 16 * 64; i += 256)
            Is[i >> 6][i & 63] = x[(row0 + (i >> 6)) * HD + (i & 63)];
        __syncthreads();
        int c = t & 63, r4 = t >> 6;
        float a0 = 0.f, a1 = 0.f, a2 = 0.f, a3 = 0.f;
#pragma unroll
        for (int k = 0; k < 64; ++k) {
            float w = Ws[k][c];
            a0 += Is[r4 + 0][k] * w;
            a1 += Is[r4 + 4][k] * w;
            a2 += Is[r4 + 8][k] * w;
            a3 += Is[r4 + 12][k] * w;
        }
        h32[(row0 + r4 + 0) * HD + c] = a0;
        h32[(row0 + r4 + 4) * HD + c] = a1;
        h32[(row0 + r4 + 8) * HD + c] = a2;
        h32[(row0 + r4 + 12) * HD + c] = a3;
    } else {
        __shared__ int cur[256];
        int tid = threadIdx.x, blk = blockIdx.x - GEMM_BLOCKS;
        cur[tid] = 0;
        __syncthreads();
        int base = blk * 4096;
#pragma unroll
        for (int k = 0; k < 16; ++k) {
            int e = base + k * 256 + tid;
            if (e < NE) {
                int c = col[e], r = row[e];
                int b = c >> 8;
                int lpos = atomicAdd(&cur[b], 1);
                int pos = counts_ex[b * NBL + blk] + lpos;
                packed[pos] = (unsigned)r | ((unsigned)(c & 255) << 16);
            }
        }
    }
}

// ---------------------------------------------------------------------------
// Fused CSR build: per 256-col bucket — (1) histogram+scan -> rowptr/dinv,
// (1.5) h16 = fp16(dinv * h32) for this bucket's rows [single rounding],
// (2) fill esrc via LDS cursors.
__global__ __launch_bounds__(256) void csr_build(const unsigned* __restrict__ packed,
                                                 const int* __restrict__ counts_ex,
                                                 int* __restrict__ rowptr,
                                                 float* __restrict__ dinv,
                                                 const float* __restrict__ h32,
                                                 __half* __restrict__ h16,
                                                 int* __restrict__ esrc) {
    __shared__ int hist[256];
    __shared__ int ws[4];
    __shared__ int lrp[256];
    __shared__ float sdinv[256];
    int bkt = blockIdx.x, tid = threadIdx.x;
    int s = counts_ex[bkt * NBL];
    int e = (bkt == NBK - 1) ? NE : counts_ex[(bkt + 1) * NBL];
    hist[tid] = 0;
    __syncthreads();
    for (int j = s + tid; j < e; j += 256)
        atomicAdd(&hist[(packed[j] >> 16) & 255], 1);
    __syncthreads();
    int lane = tid & 63, wid = tid >> 6;
    int v = hist[tid], inc = v;
#pragma unroll
    for (int off = 1; off < 64; off <<= 1) {
        int t = __shfl_up(inc, off, 64);
        if (lane >= off) inc += t;
    }
    if (lane == 63) ws[wid] = inc;
    __syncthreads();
    int woff = 0;
    for (int k = 0; k < wid; ++k) woff += ws[k];
    int excl = s + woff + inc - v;               // exclusive scan
    int node = bkt * 256 + tid;
    float dv = rsqrtf((float)(v + 1));           // +1 self-loop
    if (node < NN) {
        rowptr[node] = excl;
        dinv[node] = dv;
    }
    if (bkt == 0 && tid == 0) rowptr[NN] = NE;
    lrp[tid] = excl;
    sdinv[tid] = dv;
    hist[tid] = 0;                               // reuse as fill cursor
    __syncthreads();
    // (1.5) scale rows of this bucket: h16 = fp16(dinv * h32)
    {
        int nrows = (bkt == NBK - 1) ? (NN - 195 * 256) : 256;
        const float2* hb32 = (const float2*)(h32 + (size_t)bkt * 256 * HD);
        __half2* hb16 = (__half2*)(h16 + (size_t)bkt * 256 * HD);
        for (int i = tid; i < nrows * 32; i += 256) {
            float d = sdinv[i >> 5];
            float2 f = hb32[i];
            hb16[i] = __floats2half2_rn(d * f.x, d * f.y);
        }
    }
    // (2) fill
    for (int j = s + tid; j < e; j += 256) {
        unsigned p = packed[j];
        int lc = (p >> 16) & 255;
        int slot = lrp[lc] + atomicAdd(&hist[lc], 1);
        esrc[slot] = (int)(p & 0xFFFF);          // NN < 65536
    }
}

// ---------------------------------------------------------------------------
// h16 = dinv * (relu(in16) @ W)   (layers 2,3) — dinv in fp32 epilogue
__global__ __launch_bounds__(256) void gemm64_f16(const __half* __restrict__ in,
                                                  const float* __restrict__ W,
                                                  const float* __restrict__ dinv,
                                                  __half* __restrict__ out) {
    __shared__ float Ws[64][64];
    __shared__ float Is[16][64];
    __shared__ float sdinv[16];
    int t = threadIdx.x;
    for (int i = t; i < 64 * 64; i += 256) Ws[i >> 6][i & 63] = W[i];
    int row0 = blockIdx.x * 16;
    if (t < 16) sdinv[t] = dinv[row0 + t];
    const __half2* in2 = (const __half2*)(in + (size_t)row0 * HD);
    for (int i = t; i < 16 * 32; i += 256) {
        float2 v = __half22float2(in2[i]);
        int r = i >> 5, c2 = (i & 31) * 2;
        Is[r][c2]     = fmaxf(v.x, 0.f);
        Is[r][c2 + 1] = fmaxf(v.y, 0.f);
    }
    __syncthreads();
    int c = t & 63, r4 = t >> 6;
    float a0 = 0.f, a1 = 0.f, a2 = 0.f, a3 = 0.f;
#pragma unroll
    for (int k = 0; k < 64; ++k) {
        float w = Ws[k][c];
        a0 += Is[r4 + 0][k] * w;
        a1 += Is[r4 + 4][k] * w;
        a2 += Is[r4 + 8][k] * w;
        a3 += Is[r4 + 12][k] * w;
    }
    out[(row0 + r4 + 0) * HD + c] = __float2half(a0 * sdinv[r4 + 0]);
    out[(row0 + r4 + 4) * HD + c] = __float2half(a1 * sdinv[r4 + 4]);
    out[(row0 + r4 + 8) * HD + c] = __float2half(a2 * sdinv[r4 + 8]);
    out[(row0 + r4 + 12) * HD + c] = __float2half(a3 * sdinv[r4 + 12]);
}

// ---------------------------------------------------------------------------
// Weight-free scalar-stream gather, masked tail. ONE node per wave.
// Lane = 32*p + c: 2 edges x 32 half2 channels per VMEM; 8-edge batches give
// 4 row-gathers in flight. Remainder: ONE masked 8-edge batch (invalid slots
// clamp to the batch's first src — L1-hot — and are zero-multiplied).
template <bool POOL>
__global__ __launch_bounds__(256) void gather_mt(const __half* __restrict__ hp,
                                                 const int* __restrict__ rowptr,
                                                 const int* __restrict__ esrc,
                                                 const float* __restrict__ dinv,
                                                 const float* __restrict__ b,
                                                 __half* __restrict__ out16,
                                                 const int* __restrict__ batch,
                                                 float* __restrict__ pooled) {
    int tid = threadIdx.x, lane = tid & 63, wid = tid >> 6;
    int p = lane >> 5, c = lane & 31;           // edge-of-pair, half2 channel
    int node = __builtin_amdgcn_readfirstlane(blockIdx.x * 4 + wid);
    const __half2* hv = (const __half2*)hp;
    int s = rowptr[node], e = rowptr[node + 1];     // scalar loads
    float2 acc = {0.f, 0.f};
    int j = s;
    for (; j + 8 <= e; j += 8) {                // unmasked full batches
        int t0 = esrc[j + 0], t1 = esrc[j + 1], t2 = esrc[j + 2], t3 = esrc[j + 3];
        int t4 = esrc[j + 4], t5 = esrc[j + 5], t6 = esrc[j + 6], t7 = esrc[j + 7];
        int a0 = p ? t1 : t0;
        int a1 = p ? t3 : t2;
        int a2 = p ? t5 : t4;
        int a3 = p ? t7 : t6;
        float2 f0 = __half22float2(hv[a0 * 32 + c]);
        float2 f1 = __half22float2(hv[a1 * 32 + c]);
        float2 f2 = __half22float2(hv[a2 * 32 + c]);
        float2 f3 = __half22float2(hv[a3 * 32 + c]);
        acc.x += (f0.x + f1.x) + (f2.x + f3.x);
        acc.y += (f0.y + f1.y) + (f2.y + f3.y);
    }
    if (j < e) {                                // ONE masked batch (rem 1..7)
        // reads may run past e into later nodes' edges / the pad: values are
        // masked &0xFFFF (safe row index) and zero-multiplied when invalid.
        int t0 = esrc[j + 0] & 0xFFFF, t1 = esrc[j + 1] & 0xFFFF;
        int t2 = esrc[j + 2] & 0xFFFF, t3 = esrc[j + 3] & 0xFFFF;
        int t4 = esrc[j + 4] & 0xFFFF, t5 = esrc[j + 5] & 0xFFFF;
        int t6 = esrc[j + 6] & 0xFFFF, t7 = esrc[j + 7] & 0xFFFF;
        int i0 = j + p, i1 = j + 2 + p, i2 = j + 4 + p, i3 = j + 6 + p;
        int a0 = p ? t1 : t0;
        int a1 = p ? t3 : t2;
        int a2 = p ? t5 : t4;
        int a3 = p ? t7 : t6;
        // clamp invalid slots to t0 (same row as a valid in-flight gather)
        a0 = (i0 < e) ? a0 : t0;
        a1 = (i1 < e) ? a1 : t0;
        a2 = (i2 < e) ? a2 : t0;
        a3 = (i3 < e) ? a3 : t0;
        float m0 = (i0 < e) ? 1.f : 0.f;
        float m1 = (i1 < e) ? 1.f : 0.f;
        float m2 = (i2 < e) ? 1.f : 0.f;
        float m3 = (i3 < e) ? 1.f : 0.f;
        float2 f0 = __half22float2(hv[a0 * 32 + c]);
        float2 f1 = __half22float2(hv[a1 * 32 + c]);
        float2 f2 = __half22float2(hv[a2 * 32 + c]);
        float2 f3 = __half22float2(hv[a3 * 32 + c]);
        acc.x += m0 * f0.x + m1 * f1.x + m2 * f2.x + m3 * f3.x;
        acc.y += m0 * f0.y + m1 * f1.y + m2 * f2.y + m3 * f3.y;
    }
    // combine the two edge-pair partials (lane L ^ 32 holds same channel)
    acc.x += __shfl_xor(acc.x, 32, 64);
    acc.y += __shfl_xor(acc.y, 32, 64);
    if (p == 0) {
        float di = dinv[node];                  // scalar load
        float2 self = __half22float2(hv[node * 32 + c]);   // h' pre-scaled
        float2 bb = ((const float2*)b)[c];
        float vx = di * (acc.x + self.x) + bb.x;
        float vy = di * (acc.y + self.y) + bb.y;
        if (POOL) {
            int g = batch[node];
            atomicAdd(&pooled[g * HD + 2 * c], vx);
            atomicAdd(&pooled[g * HD + 2 * c + 1], vy);
        } else {
            ((__half2*)out16)[node * 32 + c] = __floats2half2_rn(vx, vy);
        }
    }
}

// out[g] = (pooled[g,:]/max(cnt,1)) . lin_W + lin_b   — one wave per graph
__global__ __launch_bounds__(64) void final_kernel(const float* __restrict__ pooled,
                                                   const int* __restrict__ beg,
                                                   const int* __restrict__ endx,
                                                   const float* __restrict__ lin_W,
                                                   const float* __restrict__ lin_b,
                                                   float* __restrict__ out) {
    int g = blockIdx.x, d = threadIdx.x;
    float cnt = (float)(endx[g] - beg[g]);
    float v = pooled[g * HD + d] / fmaxf(cnt, 1.f) * lin_W[d];
#pragma unroll
    for (int off = 32; off > 0; off >>= 1) v += __shfl_down(v, off, 64);
    if (d == 0) out[g] = v + lin_b[0];
}

// ---------------------------------------------------------------------------
extern "C" void kernel_launch(void* const* d_in, const int* in_sizes, int n_in,
                              void* d_out, int out_size, void* d_ws, size_t ws_size,
                              hipStream_t stream) {
    const float* x     = (const float*)d_in[0];
    const float* W1    = (const float*)d_in[1];
    const float* b1    = (const float*)d_in[2];
    const float* W2    = (const float*)d_in[3];
    const float* b2    = (const float*)d_in[4];
    const float* W3    = (const float*)d_in[5];
    const float* b3    = (const float*)d_in[6];
    const float* lin_W = (const float*)d_in[7];
    const float* lin_b = (const float*)d_in[8];
    const int* edge_index = (const int*)d_in[9];   // [2, NE]: row then col
    const int* batch      = (const int*)d_in[10];
    const int* row = edge_index;
    const int* col = edge_index + NE;
    float* out = (float*)d_out;

    // workspace layout (4B units):
    // [h32 NN*HD float][h16 NN*HD half][A16 NN*HD half][esrc NE+64][packed NE]
    // [counts M][counts_ex M][rowptr NN+2][dinv NN][bsum 256]
    // [pooled NG*HD][beg NG][endx NG]        total ~33 MB
    float*    h32       = (float*)d_ws;
    __half*   h16       = (__half*)(h32 + (size_t)NN * HD);
    __half*   A16       = h16 + (size_t)NN * HD;
    int*      esrc      = (int*)(A16 + (size_t)NN * HD);
    unsigned* packed    = (unsigned*)(esrc + NE + 64);
    int*      counts    = (int*)(packed + NE);
    int*      counts_ex = counts + M_CNT;
    int*      rowptr    = counts_ex + M_CNT;
    float*    dinv      = (float*)(rowptr + NN + 2);
    int*      bsum      = (int*)(dinv + NN);
    float*    pooled    = (float*)(bsum + 256);
    int*      beg       = (int*)(pooled + NG * HD);
    int*      endx      = beg + NG;

    // CSR build: count(+zero pooled) -> scan -> (scatter fused w/ gemm1)
    //            -> fused rowptr+scale+fill
    bucket_count<<<NBL, 256, 0, stream>>>(col, batch, counts, beg, endx, pooled);
    block_reduce<<<NBS, 256, 0, stream>>>(counts, bsum);
    scan_bsum<<<1, 64, 0, stream>>>(bsum);
    block_scan<<<NBS, 256, 0, stream>>>(counts, bsum, counts_ex);
    gemm1_scatter<<<GEMM_BLOCKS + NBL, 256, 0, stream>>>(x, W1, h32, row, col,
                                                         counts_ex, packed);
    csr_build<<<NBK, 256, 0, stream>>>(packed, counts_ex, rowptr, dinv,
                                       h32, h16, esrc);

    const int GB = NN / 4;  // gather blocks: 4 nodes (waves) each

    // Layer 1 aggregate: h16(=h1') -> A16
    gather_mt<false><<<GB, 256, 0, stream>>>(h16, rowptr, esrc, dinv, b1, A16,
                                             batch, pooled);
    // Layer 2: relu(A16) -> h16(=h2') -> A16
    gemm64_f16<<<GEMM_BLOCKS, 256, 0, stream>>>(A16, W2, dinv, h16);
    gather_mt<false><<<GB, 256, 0, stream>>>(h16, rowptr, esrc, dinv, b2, A16,
                                             batch, pooled);
    // Layer 3: relu(A16) -> h16(=h3') -> pooled (fused)
    gemm64_f16<<<GEMM_BLOCKS, 256, 0, stream>>>(A16, W3, dinv, h16);
    gather_mt<true><<<GB, 256, 0, stream>>>(h16, rowptr, esrc, dinv, b3, nullptr,
                                            batch, pooled);

    final_kernel<<<NG, 64, 0, stream>>>(pooled, beg, endx, lin_W, lin_b, out);
}